// Round 3
// baseline (5646.150 us; speedup 1.0000x reference)
//
#include <hip/hip_runtime.h>
#include <cstdint>
#include <cstddef>

// ---------------------------------------------------------------------------
// 2-layer LSTM, T=512, B=64, IN=H=1024. Persistent kernel, 256 blocks x 512
// threads, layers pipelined at lag 1, split into TWO independent half-batch
// pipelines (batches 0-31 / 32-63).
// R7 changes (theory: R6's remaining step time = L1's fat stage — 256 KB of
// reads/block of which 128 KB is agent-scope L2-BYPASS h2 ring loads that
// can't L2-merge — plus 64 idle CUs):
//  - L1 split into 2 batch-group replicas, 64 blocks x 16 units x 32 batches,
//    structurally identical to L0. Grid 256 = all CUs. L1 reads halve, gate
//    fan-in drops to 16 producers/wave, two pipelines fully decoupled.
//  - h2 given a full 513-slab history (like h1) when ws_size permits:
//    addresses never reused -> plain, L2-mergeable loads (same coherence
//    argument as h1). Kernel templated on HIST; launch picks full-history if
//    ws_size >= 135 MB else the proven ring-4 + agent-atomic-load fallback.
//  - Ring fallback WAR invariant preserved: each L1 block's four h2-waves
//    gate on peer groups 0-3 -> union at the pre-write barrier = all 64
//    same-pipeline peers >= s.
// ---------------------------------------------------------------------------

typedef _Float16 f16;
typedef _Float16 f16x8 __attribute__((ext_vector_type(8)));
typedef _Float16 f16x4 __attribute__((ext_vector_type(4)));
typedef float    f32x4 __attribute__((ext_vector_type(4)));
typedef unsigned long long u64;

#define T_STEPS 512
#define BH      65536                 /* 64 batch x 1024 hidden */
#define NBLK    256

// workspace layout (bytes)
static const size_t OFF_FLAG   = 0;          // 256 x 4 B flags
static const size_t OFF_H2RING = 0x1000;     // ring fallback: 4 slabs * 128 KB
static const size_t OFF_H1     = 0x90000;    // h1 history: 513 * 128 KB = 64.125 MB
static const size_t OFF_H2BIG  = 0x40B0000;  // h2 history: 513 * 128 KB
static const size_t WS_NEED_BIG = 0x80D0000; // ~135 MB
// h1 slab layout: slab*65536 + (b>>5)*32768 + (k>>3)*256 + (b&31)*8 + (k&7)  (f16)
// h2 slab layout: identical (p = b>>5 region-major).

// ---------------------------------------------------------------------------
__global__ void prep_kernel(f16* __restrict__ h1, unsigned* __restrict__ flags)
{
    const int NONES = BH / 4;                 // h1 slab 0 = ones (h init)
    const int NZ    = 256 / 4;
    int tid    = blockIdx.x * blockDim.x + threadIdx.x;
    int stride = gridDim.x * blockDim.x;
    f16x4 one = { (f16)1.f, (f16)1.f, (f16)1.f, (f16)1.f };
    uint4 z = { 0u, 0u, 0u, 0u };
    for (int i = tid; i < NONES + NZ; i += stride) {
        if (i < NONES) ((f16x4*)h1)[i] = one;
        else           ((uint4*)flags)[i - NONES] = z;
    }
}

__device__ __forceinline__ float sigm(float x) { return 1.f/(1.f + __expf(-x)); }
__device__ __forceinline__ float tanh_f(float x) {
    float e = __expf(-2.f*fabsf(x));
    float r = (1.f - e)/(1.f + e);
    return x >= 0.f ? r : -r;
}
__device__ __forceinline__ f16x8 cvt8(float4 a, float4 b) {
    f16x8 r;
    r[0]=(f16)a.x; r[1]=(f16)a.y; r[2]=(f16)a.z; r[3]=(f16)a.w;
    r[4]=(f16)b.x; r[5]=(f16)b.y; r[6]=(f16)b.z; r[7]=(f16)b.w;
    return r;
}

// L2-bypass (device-scope) poll load.
__device__ __forceinline__ unsigned poll1(const unsigned* p) {
    unsigned r;
    asm volatile("global_load_dword %0, %1, off sc1\n\ts_waitcnt vmcnt(0)"
                 : "=v"(r) : "v"(p) : "memory");
    return r;
}
// L2-bypass (device-scope) flag publish.
__device__ __forceinline__ void flag_store(unsigned* p, unsigned v) {
    asm volatile("global_store_dword %0, %1, off sc1" :: "v"(p), "v"(v) : "memory");
}
// Coherent 16-B load as 2x agent-scope u64 (ring mode only: ring reuses
// addresses so the consumer's per-XCD L2 could hold stale lines).
__device__ __forceinline__ f16x8 ald16(const f16* p) {
    union { u64 q[2]; f16x8 v; } u;
    u.q[0] = __hip_atomic_load((const u64*)p,       __ATOMIC_RELAXED, __HIP_MEMORY_SCOPE_AGENT);
    u.q[1] = __hip_atomic_load((const u64*)(p + 4), __ATOMIC_RELAXED, __HIP_MEMORY_SCOPE_AGENT);
    return u.v;
}
template<int HIST> __device__ __forceinline__ f16x8 h2ld(const f16* p) {
    if constexpr (HIST) return *(const f16x8*)p;
    else                return ald16(p);
}

// ---------------------------------------------------------------------------
// Partition (two independent pipelines p=0,1 over batch halves):
//  Layer 0 (bid 0..127): p = bid>>6, jg = bid&63 (16 units j0=jg*16),
//    32 batches. 8 waves = 8 K-slices of 256 over K=2048 [x | h1]; waves
//    0-3 = x (ungated), waves 4-7 = h1, each gated on its 16 producers.
//  Layer 1 (bid 128..255): p = (bid-128)>>6, jg1 = (bid-128)&63 (16 units),
//    32 batches. waves 0-3 = h1 K-slices (gated on 16 L0 producers of
//    pipeline p), waves 4-7 = h2 (gated on 16 L1 producers; ones at s==1).
// Step s: L0 computes h1 token s -> slab s+1; L1 computes out token s-1
//    (h1 slab s + h2 slab s-1), writes out + h2 slab s.
// ---------------------------------------------------------------------------
template<int HIST>
__global__ __launch_bounds__(512, 2)
void lstm_kernel(const float* __restrict__ x,
                 const float* __restrict__ wih0, const float* __restrict__ whh0,
                 const float* __restrict__ b0,
                 const float* __restrict__ wih1, const float* __restrict__ whh1,
                 const float* __restrict__ b1,
                 f16* __restrict__ h1, f16* __restrict__ h2,
                 float* __restrict__ out, unsigned* __restrict__ flags)
{
    __shared__ float lds_part[16384];   // 8 wave-regions x 2048 floats
    __shared__ float lds_out[2048];

    const int tid   = threadIdx.x;
    const int bid   = blockIdx.x;
    const int wave  = tid >> 6, lane = tid & 63;
    const int l15   = lane & 15, l4 = lane >> 4;
    const f32x4 zz = { 0.f, 0.f, 0.f, 0.f };

    if (bid < 128) {
        // =================== LAYER 0 ===================
        const int bg = bid >> 6, jg = bid & 63, j0 = jg << 4;
        const int kq = wave;                    // 0..3: x-slice, 4..7: h-slice

        f16x8 Bf[32];
        f32x4 acc[8];
        {
            const float* wsrc = (kq < 4) ? wih0 : whh0;
            const int kp = (kq & 3) * 256;
#pragma unroll
            for (int nt = 0; nt < 4; nt++) {
                const float* rp = wsrc + (size_t)(nt*1024 + j0 + l15)*1024 + kp + l4*8;
#pragma unroll
                for (int kc = 0; kc < 8; kc++) {
                    float4 a = *(const float4*)(rp + kc*32);
                    float4 b = *(const float4*)(rp + kc*32 + 4);
                    Bf[nt*8 + kc] = cvt8(a, b);
                }
            }
#pragma unroll
            for (int i = 0; i < 32; i++) asm volatile("" : "+v"(Bf[i]));
        }

        const int u  = ((tid >> 8) << 3) | (tid & 7);   // unit 0..15
        const int bm = (tid >> 3) & 31;                 // batch-in-group 0..31
        const float bi  = b0[j0+u],      bff = b0[1024+j0+u];
        const float bgg = b0[2048+j0+u], boo = b0[3072+j0+u];
        float c = 0.f;
        const int m_ = bm >> 4, r_ = bm & 15;
        const int lanei = ((r_ >> 2) << 4) | u, rr = r_ & 3;

        for (int s = 0; s <= T_STEPS; s++) {
            const bool act = (s < T_STEPS);
            if (act) {
#pragma unroll
                for (int i = 0; i < 8; i++) acc[i] = zz;
                if (kq < 4) {
                    // ---- x-part: ungated, overlaps peers' straggle ----
                    const float* a0 = x + (size_t)s*BH + (size_t)(bg*32 + l15)*1024 + kq*256 + l4*8;
                    const float* a1 = a0 + 16*1024;
#pragma unroll
                    for (int kc = 0; kc < 8; kc++) {
                        f16x8 A0 = cvt8(*(const float4*)(a0 + kc*32), *(const float4*)(a0 + kc*32 + 4));
                        f16x8 A1 = cvt8(*(const float4*)(a1 + kc*32), *(const float4*)(a1 + kc*32 + 4));
#pragma unroll
                        for (int nt = 0; nt < 4; nt++) {
                            acc[nt]   = __builtin_amdgcn_mfma_f32_16x16x32_f16(A0, Bf[nt*8+kc], acc[nt],   0,0,0);
                            acc[4+nt] = __builtin_amdgcn_mfma_f32_16x16x32_f16(A1, Bf[nt*8+kc], acc[4+nt], 0,0,0);
                        }
                    }
                } else {
                    // ---- h-part: gate on the 16 producers of this K-slice ----
                    if (s > 0) {
                        const bool mine = (lane < 16);
                        const int  pj   = ((kq - 4) << 4) + l15;     // producer jg
                        const bool skip = (!mine) || (pj == jg);
                        const unsigned* p = flags + bg*64 + (mine ? pj : 0);
                        for (;;) {
                            unsigned v = poll1(p);
                            if (__all(skip || (v >= (unsigned)s))) break;
                            __builtin_amdgcn_s_sleep(2);
                        }
                    }
                    const f16* a0 = h1 + (size_t)s*BH + bg*32768 + ((kq-4)*32 + l4)*256 + l15*8;
                    const f16* a1 = a0 + 128;
#pragma unroll
                    for (int kc = 0; kc < 8; kc++) {
                        f16x8 A0 = *(const f16x8*)(a0 + kc*1024);
                        f16x8 A1 = *(const f16x8*)(a1 + kc*1024);
#pragma unroll
                        for (int nt = 0; nt < 4; nt++) {
                            acc[nt]   = __builtin_amdgcn_mfma_f32_16x16x32_f16(A0, Bf[nt*8+kc], acc[nt],   0,0,0);
                            acc[4+nt] = __builtin_amdgcn_mfma_f32_16x16x32_f16(A1, Bf[nt*8+kc], acc[4+nt], 0,0,0);
                        }
                    }
                }
                const int pb = wave*2048 + lane*4;
#pragma unroll
                for (int i = 0; i < 8; i++)
                    *(f32x4*)&lds_part[pb + i*256] = acc[i];
            }
            __syncthreads();
            if (act) {
                f32x4 sum = *(const f32x4*)&lds_part[tid*4];
#pragma unroll
                for (int q = 1; q < 8; q++)
                    sum += *(const f32x4*)&lds_part[q*2048 + tid*4];
                *(f32x4*)&lds_out[tid*4] = sum;
            }
            __syncthreads();
            if (act) {
                float gi = lds_out[(m_*4+0)*256 + lanei*4 + rr] + bi;
                float gf = lds_out[(m_*4+1)*256 + lanei*4 + rr] + bff;
                float gg = lds_out[(m_*4+2)*256 + lanei*4 + rr] + bgg;
                float go = lds_out[(m_*4+3)*256 + lanei*4 + rr] + boo;
                float iv = sigm(gi), fv = sigm(gf), gv = tanh_f(gg), ov = sigm(go);
                c = fv*c + iv*gv;
                float h = ov * tanh_f(c);
                f16 hv = (f16)h;
                short hs = __builtin_bit_cast(short, hv);
                __hip_atomic_store((short*)(h1 + (size_t)(s+1)*BH + bg*32768 + jg*512 + tid),
                                   hs, __ATOMIC_RELAXED, __HIP_MEMORY_SCOPE_AGENT);
            }
            __builtin_amdgcn_s_waitcnt(0);   // drain h1 stores
            __syncthreads();
            if (tid == 0) flag_store(flags + bid, (unsigned)(s + 1));
        }
    } else {
        // =================== LAYER 1 ===================
        const int p_  = (bid - 128) >> 6, jg1 = (bid - 128) & 63, j0 = jg1 << 4;
        const int ks  = wave;                   // 0..3: h1-slice, 4..7: h2-slice

        f16x8 Bf[32];
        f32x4 acc[8];
        {
            const float* wsrc = (ks < 4) ? wih1 : whh1;
            const int kp = (ks & 3) * 256;
#pragma unroll
            for (int nt = 0; nt < 4; nt++) {
                const float* rp = wsrc + (size_t)(nt*1024 + j0 + l15)*1024 + kp + l4*8;
#pragma unroll
                for (int kc = 0; kc < 8; kc++) {
                    float4 a = *(const float4*)(rp + kc*32);
                    float4 b = *(const float4*)(rp + kc*32 + 4);
                    Bf[nt*8 + kc] = cvt8(a, b);
                }
            }
#pragma unroll
            for (int i = 0; i < 32; i++) asm volatile("" : "+v"(Bf[i]));
        }

        const int u  = ((tid >> 8) << 3) | (tid & 7);   // unit 0..15
        const int bm = (tid >> 3) & 31;                 // batch-in-group 0..31
        const float bi  = b1[j0+u],      bff = b1[1024+j0+u];
        const float bgg = b1[2048+j0+u], boo = b1[3072+j0+u];
        float c = 0.f;
        const int m_ = bm >> 4, r_ = bm & 15;
        const int lanei = ((r_ >> 2) << 4) | u, rr = r_ & 3;

        for (int s = 0; s <= T_STEPS; s++) {
            const bool act = (s >= 1);
            if (act) {
#pragma unroll
                for (int i = 0; i < 8; i++) acc[i] = zz;
                if (ks < 4) {
                    // ---- h1 input: gate on the 16 L0 producers of this slice ----
                    {
                        const bool mine = (lane < 16);
                        const int  pidx = p_*64 + (ks << 4) + l15;
                        const unsigned* pp = flags + (mine ? pidx : 0);
                        for (;;) {
                            unsigned v = poll1(pp);
                            if (__all(!mine || (v >= (unsigned)s))) break;
                            __builtin_amdgcn_s_sleep(2);
                        }
                    }
                    const f16* a0 = h1 + (size_t)s*BH + p_*32768 + (ks*32 + l4)*256 + l15*8;
                    const f16* a1 = a0 + 128;
#pragma unroll
                    for (int kc = 0; kc < 8; kc++) {
                        f16x8 A0 = *(const f16x8*)(a0 + kc*1024);
                        f16x8 A1 = *(const f16x8*)(a1 + kc*1024);
#pragma unroll
                        for (int nt = 0; nt < 4; nt++) {
                            acc[nt]   = __builtin_amdgcn_mfma_f32_16x16x32_f16(A0, Bf[nt*8+kc], acc[nt],   0,0,0);
                            acc[4+nt] = __builtin_amdgcn_mfma_f32_16x16x32_f16(A1, Bf[nt*8+kc], acc[4+nt], 0,0,0);
                        }
                    }
                } else if (s == 1) {
                    // h2 init = ones (token -1)
                    f16x8 A1s;
#pragma unroll
                    for (int e = 0; e < 8; e++) A1s[e] = (f16)1.f;
#pragma unroll
                    for (int kc = 0; kc < 8; kc++) {
#pragma unroll
                        for (int nt = 0; nt < 4; nt++) {
                            acc[nt]   = __builtin_amdgcn_mfma_f32_16x16x32_f16(A1s, Bf[nt*8+kc], acc[nt],   0,0,0);
                            acc[4+nt] = __builtin_amdgcn_mfma_f32_16x16x32_f16(A1s, Bf[nt*8+kc], acc[4+nt], 0,0,0);
                        }
                    }
                } else {
                    // ---- h2 recurrence: gate on the 16 L1 producers (skip own) ----
                    {
                        const bool mine = (lane < 16);
                        const int  pj   = ((ks - 4) << 4) + l15;     // producer jg1
                        const bool skip = (!mine) || (pj == jg1);
                        const unsigned* pp = flags + 128 + p_*64 + (mine ? pj : 0);
                        for (;;) {
                            unsigned v = poll1(pp);
                            if (__all(skip || (v >= (unsigned)s))) break;
                            __builtin_amdgcn_s_sleep(2);
                        }
                    }
                    const size_t slab = HIST ? (size_t)(s - 1) : (size_t)((s - 1) & 3);
                    const f16* a0 = h2 + slab*BH + p_*32768 + ((ks-4)*32 + l4)*256 + l15*8;
                    const f16* a1 = a0 + 128;
#pragma unroll
                    for (int kc = 0; kc < 8; kc++) {
                        f16x8 A0 = h2ld<HIST>(a0 + kc*1024);
                        f16x8 A1 = h2ld<HIST>(a1 + kc*1024);
#pragma unroll
                        for (int nt = 0; nt < 4; nt++) {
                            acc[nt]   = __builtin_amdgcn_mfma_f32_16x16x32_f16(A0, Bf[nt*8+kc], acc[nt],   0,0,0);
                            acc[4+nt] = __builtin_amdgcn_mfma_f32_16x16x32_f16(A1, Bf[nt*8+kc], acc[4+nt], 0,0,0);
                        }
                    }
                }
                const int pb = wave*2048 + lane*4;
#pragma unroll
                for (int i = 0; i < 8; i++)
                    *(f32x4*)&lds_part[pb + i*256] = acc[i];
            }
            __syncthreads();
            if (act) {
                f32x4 sum = *(const f32x4*)&lds_part[tid*4];
#pragma unroll
                for (int q = 1; q < 8; q++)
                    sum += *(const f32x4*)&lds_part[q*2048 + tid*4];
                *(f32x4*)&lds_out[tid*4] = sum;
            }
            __syncthreads();
            if (act) {
                float gi = lds_out[(m_*4+0)*256 + lanei*4 + rr] + bi;
                float gf = lds_out[(m_*4+1)*256 + lanei*4 + rr] + bff;
                float gg = lds_out[(m_*4+2)*256 + lanei*4 + rr] + bgg;
                float go = lds_out[(m_*4+3)*256 + lanei*4 + rr] + boo;
                float iv = sigm(gi), fv = sigm(gf), gv = tanh_f(gg), ov = sigm(go);
                c = fv*c + iv*gv;
                float h = ov * tanh_f(c);
                f16 hv = (f16)h;
                short hs = __builtin_bit_cast(short, hv);
                const size_t wslab = HIST ? (size_t)s : (size_t)(s & 3);
                __hip_atomic_store((short*)(h2 + wslab*BH + p_*32768 + jg1*512 + tid),
                                   hs, __ATOMIC_RELAXED, __HIP_MEMORY_SCOPE_AGENT);
                out[(size_t)(s-1)*BH + (size_t)(p_*32 + bm)*1024 + j0 + u] = h;  // pure output
            }
            __builtin_amdgcn_s_waitcnt(0);   // drain h2 stores before publish
            __syncthreads();
            if (tid == 0) flag_store(flags + bid, (unsigned)(s + 1));
        }
    }
}

extern "C" void kernel_launch(void* const* d_in, const int* in_sizes, int n_in,
                              void* d_out, int out_size, void* d_ws, size_t ws_size,
                              hipStream_t stream) {
    const float* x    = (const float*)d_in[0];
    const float* wih0 = (const float*)d_in[1];
    const float* whh0 = (const float*)d_in[2];
    const float* b0   = (const float*)d_in[3];
    const float* wih1 = (const float*)d_in[4];
    const float* whh1 = (const float*)d_in[5];
    const float* b1   = (const float*)d_in[6];
    float* out = (float*)d_out;

    char* ws = (char*)d_ws;
    unsigned* flags = (unsigned*)(ws + OFF_FLAG);
    f16* h1         = (f16*)(ws + OFF_H1);
    const bool big  = (ws_size >= WS_NEED_BIG);
    f16* h2         = (f16*)(ws + (big ? OFF_H2BIG : OFF_H2RING));

    prep_kernel<<<256, 256, 0, stream>>>(h1, flags);
    if (big)
        lstm_kernel<1><<<NBLK, 512, 0, stream>>>(x, wih0, whh0, b0, wih1, whh1, b1,
                                                 h1, h2, out, flags);
    else
        lstm_kernel<0><<<NBLK, 512, 0, stream>>>(x, wih0, whh0, b0, wih1, whh1, b1,
                                                 h1, h2, out, flags);
}